// Round 4
// baseline (12999.628 us; speedup 1.0000x reference)
//
#include <hip/hip_runtime.h>

// B=8, S=1024, H=16, DK=64, D=1024. Input/output storage dtype is UNKNOWN
// (reference says fp32; harness label says bf16) -> runtime device-side
// detection (flag in ws): 0 = bf16 storage, 1 = fp32 storage.
#define SS 1024
#define HH 16
#define DDK 64
#define DD 1024

typedef unsigned short u16t;
typedef unsigned short us8 __attribute__((ext_vector_type(8)));
typedef unsigned short us4 __attribute__((ext_vector_type(4)));

__device__ __forceinline__ float bf2f(u16t u) {
    return __uint_as_float(((unsigned int)u) << 16);
}
__device__ __forceinline__ u16t f2bf(float f) {
    unsigned int u = __float_as_uint(f);
    return (u16t)((u + 0x7fffu + ((u >> 16) & 1u)) >> 16);  // RTNE
}

// ---- runtime input-dtype detect ----------------------------------------
// Even u16 elements: real bf16 data ~N(0,1) -> exponent ~126 (sane).
// fp32 storage -> even u16 = low mantissa bits -> uniform exponent (12.5% sane).
__global__ void detect_kernel(const void* x, int* flag) {
    int tid = threadIdx.x;  // 64 threads, one wave
    u16t u = ((const u16t*)x)[2 * tid];
    int e = (u >> 7) & 0xFF;
    bool sane = (e >= 112 && e <= 143);
    unsigned long long m = __ballot(sane);
    if (tid == 0) flag[0] = (__builtin_popcountll(m) < 32) ? 1 : 0;
}

__device__ __forceinline__ float ld1(const void* p, size_t i, int f) {
    return f ? ((const float*)p)[i] : bf2f(((const u16t*)p)[i]);
}
__device__ __forceinline__ void ld4v(const void* p, size_t i, int f, float* o) {
    if (f) {
        float4 a = *(const float4*)((const float*)p + i);
        o[0] = a.x; o[1] = a.y; o[2] = a.z; o[3] = a.w;
    } else {
        us4 v = *(const us4*)((const u16t*)p + i);
        o[0] = bf2f(v[0]); o[1] = bf2f(v[1]); o[2] = bf2f(v[2]); o[3] = bf2f(v[3]);
    }
}
__device__ __forceinline__ void ld8v(const void* p, size_t i, int f, float* o) {
    if (f) {
        const float* q = (const float*)p + i;
        float4 a = *(const float4*)q, b = *(const float4*)(q + 4);
        o[0] = a.x; o[1] = a.y; o[2] = a.z; o[3] = a.w;
        o[4] = b.x; o[5] = b.y; o[6] = b.z; o[7] = b.w;
    } else {
        us8 v = *(const us8*)((const u16t*)p + i);
#pragma unroll
        for (int j = 0; j < 8; j++) o[j] = bf2f(v[j]);
    }
}

// ---------------- LayerNorm: x[8192][D] -> xn bf16 (internal) ------------
__global__ __launch_bounds__(256) void ln_kernel(const void* x, u16t* xn,
                                                 const int* flagp) {
    const int f = flagp[0];
    int row = blockIdx.x, tid = threadIdx.x;
    float v[4];
    ld4v(x, (size_t)row * DD + tid * 4, f, v);
    float s = v[0] + v[1] + v[2] + v[3];
    __shared__ float red[8];
    for (int o = 32; o > 0; o >>= 1) s += __shfl_down(s, o);
    int wave = tid >> 6, lane = tid & 63;
    if (lane == 0) red[wave] = s;
    __syncthreads();
    float mu = (red[0] + red[1] + red[2] + red[3]) * (1.0f / DD);
    float d0 = v[0] - mu, d1 = v[1] - mu, d2 = v[2] - mu, d3 = v[3] - mu;
    float q = d0 * d0 + d1 * d1 + d2 * d2 + d3 * d3;
    for (int o = 32; o > 0; o >>= 1) q += __shfl_down(q, o);
    if (lane == 0) red[wave + 4] = q;
    __syncthreads();
    float var = (red[4] + red[5] + red[6] + red[7]) * (1.0f / DD);
    float rs = rsqrtf(var + 1e-5f);
    us4 ov;
    ov[0] = f2bf(d0 * rs); ov[1] = f2bf(d1 * rs);
    ov[2] = f2bf(d2 * rs); ov[3] = f2bf(d3 * rs);
    *(us4*)(xn + (size_t)row * DD + tid * 4) = ov;
}

// -------- QKV projection, one batch; out layout [H,S,DK]. grid (48,16) ---
__global__ __launch_bounds__(256) void qkv_kernel(
    const u16t* __restrict__ A, const void* wq, const void* wk, const void* wv,
    const void* bq, const void* bk, const void* bv,
    u16t* qo, u16t* ko, u16t* vo, const int* flagp) {
    const int f = flagp[0];
    int wsel = blockIdx.x >> 4;
    const void* W = (wsel == 0) ? wq : (wsel == 1) ? wk : wv;
    const void* bias = (wsel == 0) ? bq : (wsel == 1) ? bk : bv;
    u16t* outp = (wsel == 0) ? qo : (wsel == 1) ? ko : vo;
    __shared__ float As[32][68];
    __shared__ float Ws[32][68];
    int tid = threadIdx.x, tx = tid & 15, ty = tid >> 4;
    int r0 = blockIdx.y * 64, o0 = (blockIdx.x & 15) * 64;
    int lr = tid >> 2, lseg = (tid & 3) * 8;
    const u16t* ap = A + (size_t)(r0 + lr) * DD + lseg;
    float acc[4][4] = {};
    for (int d0 = 0; d0 < DD; d0 += 32) {
        us8 av = *(const us8*)(ap + d0);
        float wv8[8];
        ld8v(W, (size_t)(o0 + lr) * DD + d0 + lseg, f, wv8);
        __syncthreads();
#pragma unroll
        for (int j = 0; j < 8; j++) {
            As[lseg + j][lr] = bf2f(av[j]);
            Ws[lseg + j][lr] = wv8[j];
        }
        __syncthreads();
#pragma unroll
        for (int d = 0; d < 32; d++) {
            float ar[4], wr[4];
            *(float4*)ar = *(const float4*)&As[d][ty * 4];
            *(float4*)wr = *(const float4*)&Ws[d][tx * 4];
#pragma unroll
            for (int i = 0; i < 4; i++)
#pragma unroll
                for (int j = 0; j < 4; j++) acc[i][j] += ar[i] * wr[j];
        }
    }
#pragma unroll
    for (int i = 0; i < 4; i++) {
        int r = r0 + ty * 4 + i, oo = o0 + tx * 4;
        us4 ov;
#pragma unroll
        for (int j = 0; j < 4; j++) ov[j] = f2bf(acc[i][j] + ld1(bias, oo + j, f));
        int h = oo >> 6, kk = oo & 63;
        *(us4*)(outp + ((size_t)h * SS + r) * DDK + kk) = ov;
    }
}

// ------- colsum[h][t] = sum_s exp(masked score[s][t]); grid (16,16) ------
__global__ __launch_bounds__(256) void colstats_kernel(
    const u16t* __restrict__ q, const u16t* __restrict__ k,
    const void* mask, int moff, float* colsum, const int* flagp) {
    const int f = flagp[0];
    __shared__ float Ks[64][68], Qs[64][68], mk[64], mq[64], redl[64][17];
    int tid = threadIdx.x, tx = tid & 15, ty = tid >> 4;
    int h = blockIdx.y, t0 = blockIdx.x * 64;
    int tl = tid >> 2, kseg = (tid & 3) * 16;
    {
        const u16t* kp = k + ((size_t)h * SS + t0 + tl) * DDK + kseg;
        us8 v0 = *(const us8*)kp, v1 = *(const us8*)(kp + 8);
#pragma unroll
        for (int j = 0; j < 8; j++) {
            Ks[kseg + j][tl] = bf2f(v0[j]);
            Ks[kseg + 8 + j][tl] = bf2f(v1[j]);
        }
        if (tid < 64) mk[tid] = ld1(mask, moff + t0 + tid, f);
    }
    float l4[4] = {0.f, 0.f, 0.f, 0.f};
    for (int s0 = 0; s0 < SS; s0 += 64) {
        const u16t* qp = q + ((size_t)h * SS + s0 + tl) * DDK + kseg;
        us8 v0 = *(const us8*)qp, v1 = *(const us8*)(qp + 8);
        __syncthreads();
#pragma unroll
        for (int j = 0; j < 8; j++) {
            Qs[kseg + j][tl] = bf2f(v0[j]);
            Qs[kseg + 8 + j][tl] = bf2f(v1[j]);
        }
        if (tid < 64) mq[tid] = ld1(mask, moff + s0 + tid, f);
        __syncthreads();
        float sc[4][4] = {};
#pragma unroll
        for (int kk = 0; kk < 64; kk++) {
            float qr[4], kr[4];
            *(float4*)qr = *(const float4*)&Qs[kk][ty * 4];
            *(float4*)kr = *(const float4*)&Ks[kk][tx * 4];
#pragma unroll
            for (int i = 0; i < 4; i++)
#pragma unroll
                for (int j = 0; j < 4; j++) sc[i][j] += qr[i] * kr[j];
        }
#pragma unroll
        for (int i = 0; i < 4; i++) {
            float mqv = mq[ty * 4 + i];
#pragma unroll
            for (int j = 0; j < 4; j++) {
                float m2 = mqv * mk[tx * 4 + j];
                if (m2 > 0.f) l4[j] += __expf(fminf(sc[i][j] * 0.125f, 60.f));
            }
        }
    }
#pragma unroll
    for (int j = 0; j < 4; j++) redl[tx * 4 + j][ty] = l4[j];
    __syncthreads();
    if (tid < 64) {
        float s = 0.f;
#pragma unroll
        for (int w = 0; w < 16; w++) s += redl[tid][w];
        colsum[(size_t)h * SS + t0 + tid] = s;
    }
}

// ------- scores recompute, double softmax, O = attn2 @ V. grid (16,16) ---
__global__ __launch_bounds__(256) void pv_kernel(
    const u16t* __restrict__ q, const u16t* __restrict__ k,
    const u16t* __restrict__ v, const void* mask, int moff,
    const float* colsum, u16t* heads_base, int goff, const int* flagp) {
    const int f = flagp[0];
    u16t* heads = heads_base + (f ? (size_t)8 * 1024 * 1024 : 0) + goff;
    __shared__ float Qs[64][68];  // [kk][s]
    __shared__ float KE[64][68];  // K-tile, then E-tile
    __shared__ float Vs[64][68];  // [t][k]
    __shared__ float mk[64], mq[64], ics[64], lred[64][17];
    int tid = threadIdx.x, tx = tid & 15, ty = tid >> 4;
    int h = blockIdx.y, s0 = blockIdx.x * 64;
    int tl = tid >> 2, kseg = (tid & 3) * 16;
    {
        const u16t* qp = q + ((size_t)h * SS + s0 + tl) * DDK + kseg;
        us8 v0 = *(const us8*)qp, v1 = *(const us8*)(qp + 8);
#pragma unroll
        for (int j = 0; j < 8; j++) {
            Qs[kseg + j][tl] = bf2f(v0[j]);
            Qs[kseg + 8 + j][tl] = bf2f(v1[j]);
        }
        if (tid < 64) mq[tid] = ld1(mask, moff + s0 + tid, f);
    }
    float acc[4][4] = {};
    float lrow[4] = {0.f, 0.f, 0.f, 0.f};
    for (int t0 = 0; t0 < SS; t0 += 64) {
        const u16t* kp = k + ((size_t)h * SS + t0 + tl) * DDK + kseg;
        us8 k0 = *(const us8*)kp, k1 = *(const us8*)(kp + 8);
        const u16t* vp = v + ((size_t)h * SS + t0 + tl) * DDK + kseg;
        us8 w0 = *(const us8*)vp, w1 = *(const us8*)(vp + 8);
        __syncthreads();  // prev PV reads done
#pragma unroll
        for (int j = 0; j < 8; j++) {
            KE[kseg + j][tl] = bf2f(k0[j]);
            KE[kseg + 8 + j][tl] = bf2f(k1[j]);
            Vs[tl][kseg + j] = bf2f(w0[j]);
            Vs[tl][kseg + 8 + j] = bf2f(w1[j]);
        }
        if (tid < 64) {
            mk[tid] = ld1(mask, moff + t0 + tid, f);
            ics[tid] = 1.0f / fmaxf(colsum[(size_t)h * SS + t0 + tid], 1e-30f);
        }
        __syncthreads();  // staging visible
        float sc[4][4] = {};
#pragma unroll
        for (int kk = 0; kk < 64; kk++) {
            float qr[4], kr[4];
            *(float4*)qr = *(const float4*)&Qs[kk][ty * 4];
            *(float4*)kr = *(const float4*)&KE[kk][tx * 4];
#pragma unroll
            for (int i = 0; i < 4; i++)
#pragma unroll
                for (int j = 0; j < 4; j++) sc[i][j] += qr[i] * kr[j];
        }
        __syncthreads();  // QK^T reads of KE done; reuse as E
#pragma unroll
        for (int i = 0; i < 4; i++) {
            float mqv = mq[ty * 4 + i];
#pragma unroll
            for (int j = 0; j < 4; j++) {
                int tloc = tx * 4 + j;
                float m2 = mqv * mk[tloc];
                float e2 = 0.f;
                if (m2 > 0.f) {
                    float a1 = __expf(fminf(sc[i][j] * 0.125f, 60.f)) * ics[tloc];
                    e2 = __expf(fminf(a1, 60.f));
                }
                KE[tloc][ty * 4 + i] = e2;
                lrow[i] += e2;
            }
        }
        __syncthreads();  // E complete
#pragma unroll
        for (int t = 0; t < 64; t++) {
            float er[4], vr[4];
            *(float4*)er = *(const float4*)&KE[t][ty * 4];
            *(float4*)vr = *(const float4*)&Vs[t][tx * 4];
#pragma unroll
            for (int i = 0; i < 4; i++)
#pragma unroll
                for (int j = 0; j < 4; j++) acc[i][j] += er[i] * vr[j];
        }
    }
#pragma unroll
    for (int i = 0; i < 4; i++) lred[ty * 4 + i][tx] = lrow[i];
    __syncthreads();
    if (tid < 64) {
        float s = 0.f;
#pragma unroll
        for (int w = 0; w < 16; w++) s += lred[tid][w];
        lred[tid][16] = 1.0f / fmaxf(s, 1e-30f);
    }
    __syncthreads();
#pragma unroll
    for (int i = 0; i < 4; i++) {
        float inv = lred[ty * 4 + i][16];
        us4 ov;
#pragma unroll
        for (int j = 0; j < 4; j++) ov[j] = f2bf(acc[i][j] * inv);
        size_t off = (size_t)(s0 + ty * 4 + i) * DD + h * DDK + tx * 4;
        *(us4*)(heads + off) = ov;
    }
}

// ---- out-projection, in-place-safe: 16 rows/WG self-copied to LDS ------
// grid.x = rows/16; rbase = first row. Output dtype follows flag.
__global__ __launch_bounds__(256) void outproj_kernel(
    const u16t* heads_base, const void* W, const void* bias, const void* x,
    void* outp, const int* flagp, int rbase) {
    const int f = flagp[0];
    const u16t* A = heads_base + (f ? (size_t)8 * 1024 * 1024 : 0);
    __shared__ u16t At[1024][16];  // A^T tile: 32 KB
    __shared__ float Ws[32][68];
    int tid = threadIdx.x;
    int r0 = rbase + blockIdx.x * 16;
#pragma unroll
    for (int it = 0; it < 8; ++it) {
        int idx = it * 256 + tid;  // 2048 us8 chunks = 16 rows x 128
        int row = idx >> 7, c8 = idx & 127;
        us8 vv = *(const us8*)(A + (size_t)(r0 + row) * DD + c8 * 8);
#pragma unroll
        for (int j = 0; j < 8; j++) At[c8 * 8 + j][row] = vv[j];
    }
    __syncthreads();
    int tx = tid & 15, ty = tid >> 4;  // ty = local row
    int lr = tid >> 2, lseg = (tid & 3) * 8;
    for (int ob = 0; ob < 16; ++ob) {
        float acc[4] = {0.f, 0.f, 0.f, 0.f};
        for (int d0 = 0; d0 < DD; d0 += 32) {
            float wv8[8];
            ld8v(W, (size_t)(ob * 64 + lr) * DD + d0 + lseg, f, wv8);
            __syncthreads();
#pragma unroll
            for (int j = 0; j < 8; j++) Ws[lseg + j][lr] = wv8[j];
            __syncthreads();
#pragma unroll
            for (int d = 0; d < 32; d++) {
                float a = bf2f(At[d0 + d][ty]);
                float wr[4];
                *(float4*)wr = *(const float4*)&Ws[d][tx * 4];
#pragma unroll
                for (int j = 0; j < 4; j++) acc[j] += a * wr[j];
            }
        }
        int r = r0 + ty, oo = ob * 64 + tx * 4;
        float res[4];
        ld4v(x, (size_t)r * DD + oo, f, res);
        if (f) {
            float4 c;
            c.x = acc[0] + ld1(bias, oo + 0, 1) + res[0];
            c.y = acc[1] + ld1(bias, oo + 1, 1) + res[1];
            c.z = acc[2] + ld1(bias, oo + 2, 1) + res[2];
            c.w = acc[3] + ld1(bias, oo + 3, 1) + res[3];
            *(float4*)((float*)outp + (size_t)r * DD + oo) = c;
        } else {
            us4 ov;
#pragma unroll
            for (int j = 0; j < 4; j++)
                ov[j] = f2bf(acc[j] + ld1(bias, oo + j, 0) + res[j]);
            *(us4*)((u16t*)outp + (size_t)r * DD + oo) = ov;
        }
    }
}

extern "C" void kernel_launch(void* const* d_in, const int* in_sizes, int n_in,
                              void* d_out, int out_size, void* d_ws, size_t ws_size,
                              hipStream_t stream) {
    const void* x     = d_in[0];
    const void* mask  = d_in[1];
    const void* wq    = d_in[2];
    const void* bq    = d_in[3];
    const void* wk    = d_in[4];
    const void* bk    = d_in[5];
    const void* wv    = d_in[6];
    const void* bv    = d_in[7];
    const void* w_out = d_in[8];
    const void* b_out = d_in[9];

    // ws: qb/kb/vb 2MB each + colsum 64KB + flag. Peak 6.07 MB.
    char* ws = (char*)d_ws;
    const size_t MB = 1024 * 1024;
    u16t* qb    = (u16t*)(ws);
    u16t* kb    = (u16t*)(ws + 2 * MB);
    u16t* vb    = (u16t*)(ws + 4 * MB);
    float* csum = (float*)(ws + 6 * MB);
    int* flagp  = (int*)(ws + 6 * MB + 64 * 1024);

    // xn (bf16, internal) in d_out lower 16MB; heads bf16 at d_out (+16MB if fp32 mode).
    u16t* xn = (u16t*)d_out;

    detect_kernel<<<dim3(1), 64, 0, stream>>>(x, flagp);
    ln_kernel<<<dim3(8 * SS), 256, 0, stream>>>(x, xn, flagp);
    for (int g = 0; g < 8; g++) {
        const u16t* xng = xn + (size_t)g * SS * DD;
        int moff = g * SS;
        int goff = g * SS * DD;
        qkv_kernel<<<dim3(48, 16), 256, 0, stream>>>(xng, wq, wk, wv, bq, bk, bv,
                                                     qb, kb, vb, flagp);
        colstats_kernel<<<dim3(16, 16), 256, 0, stream>>>(qb, kb, mask, moff, csum, flagp);
        pv_kernel<<<dim3(16, 16), 256, 0, stream>>>(qb, kb, vb, mask, moff, csum,
                                                    (u16t*)d_out, goff, flagp);
    }
    // Cascade: each dispatch's fp32 writes only clobber heads rows consumed by
    // EARLIER dispatches (b <= 4096 + a/2), tail dispatches are single-WG (self-safe).
    const int rng[10][2] = {{0, 4096}, {4096, 2048}, {6144, 1024}, {7168, 512},
                            {7680, 256}, {7936, 128}, {8064, 64}, {8128, 32},
                            {8160, 16}, {8176, 16}};
    for (int i = 0; i < 10; i++) {
        outproj_kernel<<<dim3(rng[i][1] / 16), 256, 0, stream>>>(
            (const u16t*)d_out, w_out, b_out, x, d_out, flagp, rng[i][0]);
    }
}

// Round 6
// 496.805 us; speedup vs baseline: 26.1664x; 26.1664x over previous
//
#include <hip/hip_runtime.h>

// B=8, S=1024, H=16, DK=64, D=1024. Inputs/outputs fp32 (confirmed R4).
// Internal bf16 (MFMA 16x16x32), fp32 accumulate.
// heads (bf16) live at d_out bytes [16MB,32MB): row h at 16MB + 2048*h (R4-proven).
// Out-proj cascade {0,4096},{4096,2048},...,{7936,128} is race-free: dispatch
// [a,b) clobbers heads rows [2a-8192,2b-8192), always consumed earlier.
// Tail rows 8064..8191 read from a 256KB copy in ws (qb region, dead after pv).

typedef unsigned short ushort_t;
typedef unsigned short us4 __attribute__((ext_vector_type(4)));
typedef unsigned short us8 __attribute__((ext_vector_type(8)));
typedef __bf16 bf16x8 __attribute__((ext_vector_type(8)));
typedef float f32x4 __attribute__((ext_vector_type(4)));

__device__ __forceinline__ ushort_t f2bf(float f) {
    unsigned int u = __float_as_uint(f);
    return (ushort_t)((u + 0x7fffu + ((u >> 16) & 1u)) >> 16);  // RTNE
}

// async global->LDS, 16B/lane; LDS dst = wave-uniform base + lane*16
#define GLDS(gp, lp)                                                        \
    __builtin_amdgcn_global_load_lds(                                       \
        (const __attribute__((address_space(1))) unsigned int*)(gp),        \
        (__attribute__((address_space(3))) unsigned int*)(lp), 16, 0, 0)

#define MFMA(a, b, c) __builtin_amdgcn_mfma_f32_16x16x32_bf16((a), (b), (c), 0, 0, 0)

// ---------------- LayerNorm: x fp32 [8192][1024] -> xn bf16 ----------------
__global__ __launch_bounds__(256) void ln_kernel(const float* __restrict__ x,
                                                 ushort_t* __restrict__ xn) {
    int row = blockIdx.x, tid = threadIdx.x;
    float4 v = ((const float4*)(x + (size_t)row * 1024))[tid];
    float s = v.x + v.y + v.z + v.w;
    __shared__ float red[8];
    for (int o = 32; o > 0; o >>= 1) s += __shfl_down(s, o);
    int wave = tid >> 6, lane = tid & 63;
    if (lane == 0) red[wave] = s;
    __syncthreads();
    float mu = (red[0] + red[1] + red[2] + red[3]) * (1.0f / 1024.0f);
    float d0 = v.x - mu, d1 = v.y - mu, d2 = v.z - mu, d3 = v.w - mu;
    float q = d0 * d0 + d1 * d1 + d2 * d2 + d3 * d3;
    for (int o = 32; o > 0; o >>= 1) q += __shfl_down(q, o);
    if (lane == 0) red[wave + 4] = q;
    __syncthreads();
    float var = (red[4] + red[5] + red[6] + red[7]) * (1.0f / 1024.0f);
    float rs = rsqrtf(var + 1e-5f);
    us4 ov;
    ov[0] = f2bf(d0 * rs); ov[1] = f2bf(d1 * rs);
    ov[2] = f2bf(d2 * rs); ov[3] = f2bf(d3 * rs);
    ((us4*)(xn + (size_t)row * 1024))[tid] = ov;
}

// ---------------- fp32 -> bf16 convert (1M elements) -----------------------
__global__ __launch_bounds__(256) void wconv(const float* __restrict__ src,
                                             ushort_t* __restrict__ dst) {
    size_t i = ((size_t)blockIdx.x * 256 + threadIdx.x) * 4;
    float4 f = *(const float4*)(src + i);
    us4 o;
    o[0] = f2bf(f.x); o[1] = f2bf(f.y); o[2] = f2bf(f.z); o[3] = f2bf(f.w);
    *(us4*)(dst + i) = o;
}

// ------------- bf16 tail copy: 128 rows (128K ushorts) ---------------------
__global__ __launch_bounds__(256) void tailcopy(const us8* __restrict__ src,
                                                us8* __restrict__ dst) {
    size_t i = (size_t)blockIdx.x * 256 + threadIdx.x;  // 16384 us8
    dst[i] = src[i];
}

// --------- MFMA bt-GEMM: C[r][n] = sum_k A[r][k] * B[n][k] + bias[n] -------
// BMODE 0: B bf16 (async staged); 1: B fp32 (VALU convert staged)
// OMODE 0: qkv epilogue (bf16 scatter; wsel=blockIdx.z picks q/k/vt)
// OMODE 1: fp32 out + residual
template <int BMODE, int OMODE>
__global__ __launch_bounds__(256) void gemm_mfma(
    const ushort_t* __restrict__ A, const void* __restrict__ Bq,
    const void* __restrict__ Bk, const void* __restrict__ Bv,
    const float* __restrict__ biasq, const float* __restrict__ biask,
    const float* __restrict__ biasv, ushort_t* __restrict__ oq,
    ushort_t* __restrict__ ok, ushort_t* __restrict__ ovt,
    float* __restrict__ ofp, const float* __restrict__ resx, int batched,
    int r0base, int aoff) {
    __shared__ ushort_t As[128 * 32] __attribute__((aligned(16)));
    __shared__ ushort_t Bs[128 * 32] __attribute__((aligned(16)));
    int tid = threadIdx.x, w = tid >> 6, lane = tid & 63;
    int quad = lane >> 4, l15 = lane & 15;
    int wm = w & 1, wn = w >> 1;
    int n0 = blockIdx.x * 128;
    int r0 = r0base + blockIdx.y * 128;
    int wsel = blockIdx.z;
    const void* Bp = (wsel == 0) ? Bq : (wsel == 1) ? Bk : Bv;
    const float* biasp = (wsel == 0) ? biasq : (wsel == 1) ? biask : biasv;

    f32x4 acc[4][4];
#pragma unroll
    for (int i = 0; i < 4; i++)
#pragma unroll
        for (int j = 0; j < 4; j++) acc[i][j] = (f32x4){0.f, 0.f, 0.f, 0.f};

    for (int k0 = 0; k0 < 1024; k0 += 32) {
        __syncthreads();
#pragma unroll
        for (int ii = 0; ii < 2; ii++) {  // A tile 128x32 (8KB)
            int li = (w * 2 + ii) * 64 + lane;
            int row = li >> 2, kc = li & 3;
            GLDS(A + (size_t)(r0 + row - aoff) * 1024 + k0 + kc * 8,
                 &As[(w * 2 + ii) * 512]);
        }
        if (BMODE == 0) {
#pragma unroll
            for (int ii = 0; ii < 2; ii++) {
                int li = (w * 2 + ii) * 64 + lane;
                int row = li >> 2, kc = li & 3;
                GLDS((const ushort_t*)Bp + (size_t)(n0 + row) * 1024 + k0 + kc * 8,
                     &Bs[(w * 2 + ii) * 512]);
            }
        } else {
            int row = tid >> 1, half = tid & 1;
            const float* gb =
                (const float*)Bp + (size_t)(n0 + row) * 1024 + k0 + half * 16;
            float4 f0 = *(const float4*)gb;
            float4 f1 = *(const float4*)(gb + 4);
            float4 f2 = *(const float4*)(gb + 8);
            float4 f3 = *(const float4*)(gb + 12);
            us8 p0, p1;
            p0[0] = f2bf(f0.x); p0[1] = f2bf(f0.y); p0[2] = f2bf(f0.z); p0[3] = f2bf(f0.w);
            p0[4] = f2bf(f1.x); p0[5] = f2bf(f1.y); p0[6] = f2bf(f1.z); p0[7] = f2bf(f1.w);
            p1[0] = f2bf(f2.x); p1[1] = f2bf(f2.y); p1[2] = f2bf(f2.z); p1[3] = f2bf(f2.w);
            p1[4] = f2bf(f3.x); p1[5] = f2bf(f3.y); p1[6] = f2bf(f3.z); p1[7] = f2bf(f3.w);
            *(us8*)&Bs[row * 32 + half * 16] = p0;
            *(us8*)&Bs[row * 32 + half * 16 + 8] = p1;
        }
        __syncthreads();
        bf16x8 a[4], b[4];
#pragma unroll
        for (int i = 0; i < 4; i++)
            a[i] = *(const bf16x8*)&As[(wm * 64 + i * 16 + l15) * 32 + quad * 8];
#pragma unroll
        for (int j = 0; j < 4; j++)
            b[j] = *(const bf16x8*)&Bs[(wn * 64 + j * 16 + l15) * 32 + quad * 8];
#pragma unroll
        for (int i = 0; i < 4; i++)
#pragma unroll
            for (int j = 0; j < 4; j++) acc[i][j] = MFMA(a[i], b[j], acc[i][j]);
    }
    // epilogue; C layout: col=l15, row=quad*4+v
#pragma unroll
    for (int j = 0; j < 4; j++) {
        int n = n0 + wn * 64 + j * 16 + l15;
        float bj = biasp[n];
        if (OMODE == 0) {
            int h = n >> 6, kk = n & 63;
#pragma unroll
            for (int i = 0; i < 4; i++) {
#pragma unroll
                for (int v = 0; v < 4; v++) {
                    int r = r0 + wm * 64 + i * 16 + quad * 4 + v;
                    int bb = batched ? (r >> 10) : 0;
                    int s = r & 1023;
                    ushort_t val = f2bf(acc[i][j][v] + bj);
                    if (wsel < 2) {
                        ushort_t* op = (wsel == 0) ? oq : ok;
                        op[((size_t)(bb * 16 + h) * 1024 + s) * 64 + kk] = val;
                    } else {
                        ovt[((size_t)(bb * 16 + h) * 64 + kk) * 1024 + s] = val;
                    }
                }
            }
        } else {
#pragma unroll
            for (int i = 0; i < 4; i++) {
#pragma unroll
                for (int v = 0; v < 4; v++) {
                    int r = r0 + wm * 64 + i * 16 + quad * 4 + v;
                    size_t idx = (size_t)r * 1024 + n;
                    ofp[idx] = acc[i][j][v] + bj + resx[idx];
                }
            }
        }
    }
}

// --- colsum[bh][t] = sum_s exp(masked score) ; MFMA 64x64 tiles ------------
__global__ __launch_bounds__(256) void colstats_mfma(
    const ushort_t* __restrict__ qb, const ushort_t* __restrict__ kb,
    const float* __restrict__ mask, int moff, float* __restrict__ colsum) {
    __shared__ ushort_t Ks[4096] __attribute__((aligned(16)));  // [2][64][32]
    __shared__ ushort_t Qs[4096] __attribute__((aligned(16)));
    __shared__ float mk[64], mq[64], red[4][64];
    int tid = threadIdx.x, w = tid >> 6, lane = tid & 63;
    int quad = lane >> 4, l15 = lane & 15;
    int by = blockIdx.y;
    size_t qoff = (size_t)by * 65536;
    int coff = by * 1024;
    int mb = moff + (by >> 4) * 1024;
    int t0 = blockIdx.x * 64;
#pragma unroll
    for (int ii = 0; ii < 2; ii++) {
        int qq = w * 2 + ii, half = qq >> 2, sub = qq & 3;
        int li = sub * 64 + lane, row = li >> 2, seg = li & 3;
        GLDS(kb + qoff + (size_t)(t0 + row) * 64 + half * 32 + seg * 8,
             &Ks[half * 2048 + sub * 512]);
    }
    if (tid < 64) mk[tid] = mask[mb + t0 + tid];
    float colacc[4] = {0.f, 0.f, 0.f, 0.f};
    for (int s0 = 0; s0 < 1024; s0 += 64) {
        __syncthreads();
#pragma unroll
        for (int ii = 0; ii < 2; ii++) {
            int qq = w * 2 + ii, half = qq >> 2, sub = qq & 3;
            int li = sub * 64 + lane, row = li >> 2, seg = li & 3;
            GLDS(qb + qoff + (size_t)(s0 + row) * 64 + half * 32 + seg * 8,
                 &Qs[half * 2048 + sub * 512]);
        }
        if (tid < 64) mq[tid] = mask[mb + s0 + tid];
        __syncthreads();
        bf16x8 a0 = *(const bf16x8*)&Qs[(w * 16 + l15) * 32 + quad * 8];
        bf16x8 a1 = *(const bf16x8*)&Qs[2048 + (w * 16 + l15) * 32 + quad * 8];
#pragma unroll
        for (int j = 0; j < 4; j++) {
            bf16x8 b0 = *(const bf16x8*)&Ks[(j * 16 + l15) * 32 + quad * 8];
            bf16x8 b1 = *(const bf16x8*)&Ks[2048 + (j * 16 + l15) * 32 + quad * 8];
            f32x4 sc = (f32x4){0.f, 0.f, 0.f, 0.f};
            sc = MFMA(a0, b0, sc);
            sc = MFMA(a1, b1, sc);
            float mkv = mk[j * 16 + l15];
#pragma unroll
            for (int v = 0; v < 4; v++) {
                int sl = w * 16 + quad * 4 + v;
                if (mq[sl] * mkv > 0.f) colacc[j] += __expf(sc[v] * 0.125f);
            }
        }
    }
#pragma unroll
    for (int j = 0; j < 4; j++) {
        float vv = colacc[j];
        vv += __shfl_down(vv, 32);
        vv += __shfl_down(vv, 16);
        if (quad == 0) red[w][j * 16 + l15] = vv;
    }
    __syncthreads();
    if (tid < 64)
        colsum[coff + t0 + tid] = red[0][tid] + red[1][tid] + red[2][tid] + red[3][tid];
}

// --- double softmax + PV (MFMA); heads bf16, single base -------------------
__global__ __launch_bounds__(256) void pv_mfma(
    const ushort_t* __restrict__ qb, const ushort_t* __restrict__ kb,
    const ushort_t* __restrict__ vtb, const float* __restrict__ mask, int moff,
    const float* __restrict__ colsum, ushort_t* __restrict__ H, int hbase) {
    __shared__ ushort_t Qs[4096] __attribute__((aligned(16)));
    __shared__ ushort_t Ks[4096] __attribute__((aligned(16)));
    __shared__ ushort_t Vt[4096] __attribute__((aligned(16)));  // [2][64dk][32t]
    __shared__ ushort_t E[64 * 72] __attribute__((aligned(16)));
    __shared__ float mk[64], mq[64], ics[64];
    int tid = threadIdx.x, w = tid >> 6, lane = tid & 63;
    int quad = lane >> 4, l15 = lane & 15;
    int by = blockIdx.y;
    size_t qoff = (size_t)by * 65536;
    int coff = by * 1024;
    int mb = moff + (by >> 4) * 1024;
    int h = by & 15;
    int s0 = blockIdx.x * 64;
#pragma unroll
    for (int ii = 0; ii < 2; ii++) {
        int qq = w * 2 + ii, half = qq >> 2, sub = qq & 3;
        int li = sub * 64 + lane, row = li >> 2, seg = li & 3;
        GLDS(qb + qoff + (size_t)(s0 + row) * 64 + half * 32 + seg * 8,
             &Qs[half * 2048 + sub * 512]);
    }
    if (tid < 64) mq[tid] = mask[mb + s0 + tid];
    bf16x8 ones;
#pragma unroll
    for (int e = 0; e < 8; e++) ones[e] = (__bf16)1.0f;
    f32x4 acc_o[4], acc_rs = (f32x4){0.f, 0.f, 0.f, 0.f};
#pragma unroll
    for (int j = 0; j < 4; j++) acc_o[j] = (f32x4){0.f, 0.f, 0.f, 0.f};
    for (int t0 = 0; t0 < 1024; t0 += 64) {
        __syncthreads();
#pragma unroll
        for (int ii = 0; ii < 2; ii++) {
            int qq = w * 2 + ii, half = qq >> 2, sub = qq & 3;
            int li = sub * 64 + lane, row = li >> 2, seg = li & 3;
            GLDS(kb + qoff + (size_t)(t0 + row) * 64 + half * 32 + seg * 8,
                 &Ks[half * 2048 + sub * 512]);
            GLDS(vtb + qoff + (size_t)row * 1024 + t0 + half * 32 + seg * 8,
                 &Vt[half * 2048 + sub * 512]);
        }
        if (tid < 64) {
            mk[tid] = mask[mb + t0 + tid];
            ics[tid] = 1.0f / fmaxf(colsum[coff + t0 + tid], 1e-30f);
        }
        __syncthreads();
        bf16x8 a0 = *(const bf16x8*)&Qs[(w * 16 + l15) * 32 + quad * 8];
        bf16x8 a1 = *(const bf16x8*)&Qs[2048 + (w * 16 + l15) * 32 + quad * 8];
#pragma unroll
        for (int j = 0; j < 4; j++) {
            bf16x8 b0 = *(const bf16x8*)&Ks[(j * 16 + l15) * 32 + quad * 8];
            bf16x8 b1 = *(const bf16x8*)&Ks[2048 + (j * 16 + l15) * 32 + quad * 8];
            f32x4 sc = (f32x4){0.f, 0.f, 0.f, 0.f};
            sc = MFMA(a0, b0, sc);
            sc = MFMA(a1, b1, sc);
            float mkv = mk[j * 16 + l15];
            float icv = ics[j * 16 + l15];
#pragma unroll
            for (int v = 0; v < 4; v++) {
                int sl = w * 16 + quad * 4 + v;
                float e2 = 0.f;
                if (mq[sl] * mkv > 0.f)
                    e2 = __expf(fminf(__expf(sc[v] * 0.125f) * icv, 60.f));
                E[sl * 72 + j * 16 + l15] = f2bf(e2);
            }
        }
        // PV: each wave reads only its own 16-row E strip (same-wave LDS order)
        bf16x8 ea0 = *(const bf16x8*)&E[(w * 16 + l15) * 72 + quad * 8];
        bf16x8 ea1 = *(const bf16x8*)&E[(w * 16 + l15) * 72 + 32 + quad * 8];
#pragma unroll
        for (int j = 0; j < 4; j++) {
            bf16x8 b0 = *(const bf16x8*)&Vt[(j * 16 + l15) * 32 + quad * 8];
            bf16x8 b1 = *(const bf16x8*)&Vt[2048 + (j * 16 + l15) * 32 + quad * 8];
            acc_o[j] = MFMA(ea0, b0, acc_o[j]);
            acc_o[j] = MFMA(ea1, b1, acc_o[j]);
        }
        acc_rs = MFMA(ea0, ones, acc_rs);
        acc_rs = MFMA(ea1, ones, acc_rs);
    }
#pragma unroll
    for (int v = 0; v < 4; v++) {
        int sl = w * 16 + quad * 4 + v;
        int hr = hbase + (by >> 4) * 1024 + s0 + sl;
        ushort_t* hp = H + (size_t)hr * 1024;
        float inv = 1.0f / fmaxf(acc_rs[v], 1e-30f);
#pragma unroll
        for (int j = 0; j < 4; j++)
            hp[h * 64 + j * 16 + l15] = f2bf(acc_o[j][v] * inv);
    }
}

extern "C" void kernel_launch(void* const* d_in, const int* in_sizes, int n_in,
                              void* d_out, int out_size, void* d_ws, size_t ws_size,
                              hipStream_t stream) {
    const float* x     = (const float*)d_in[0];
    const float* mask  = (const float*)d_in[1];
    const float* wq    = (const float*)d_in[2];
    const float* bq    = (const float*)d_in[3];
    const float* wk    = (const float*)d_in[4];
    const float* bk    = (const float*)d_in[5];
    const float* wv    = (const float*)d_in[6];
    const float* bv    = (const float*)d_in[7];
    const float* w_out = (const float*)d_in[8];
    const float* b_out = (const float*)d_in[9];
    float* outp = (float*)d_out;

    const size_t MB = 1024 * 1024;
    ushort_t* xn = (ushort_t*)d_out;             // bytes [0,16MB), dead after qkv
    ushort_t* H  = (ushort_t*)d_out + 8 * MB;    // heads bf16, bytes [16MB,32MB)
    char* ws = (char*)d_ws;
    ushort_t* hcopy = (ushort_t*)ws;             // 256KB tail copy (aliases qb, dead)

    // cascade: {start_row, blocksY}; all clobbered heads rows consumed earlier
    const int casc[6][2] = {{0, 32},    {4096, 16}, {6144, 8},
                            {7168, 4},  {7680, 2},  {7936, 1}};

    ln_kernel<<<dim3(8192), 256, 0, stream>>>(x, xn);

    if (ws_size >= 58 * MB) {
        ushort_t* qb  = (ushort_t*)ws;             // 16 MB
        ushort_t* kb  = (ushort_t*)(ws + 16 * MB); // 16 MB
        ushort_t* vtb = (ushort_t*)(ws + 32 * MB); // 16 MB
        float* csum   = (float*)(ws + 48 * MB);    // 512 KB
        ushort_t* wqb = (ushort_t*)(ws + 49 * MB);
        ushort_t* wkb = (ushort_t*)(ws + 51 * MB);
        ushort_t* wvb = (ushort_t*)(ws + 53 * MB);
        ushort_t* wob = (ushort_t*)(ws + 55 * MB);
        wconv<<<dim3(1024), 256, 0, stream>>>(wq, wqb);
        wconv<<<dim3(1024), 256, 0, stream>>>(wk, wkb);
        wconv<<<dim3(1024), 256, 0, stream>>>(wv, wvb);
        wconv<<<dim3(1024), 256, 0, stream>>>(w_out, wob);
        gemm_mfma<0, 0><<<dim3(8, 64, 3), 256, 0, stream>>>(
            xn, wqb, wkb, wvb, bq, bk, bv, qb, kb, vtb, nullptr, nullptr, 1, 0, 0);
        colstats_mfma<<<dim3(16, 128), 256, 0, stream>>>(qb, kb, mask, 0, csum);
        pv_mfma<<<dim3(16, 128), 256, 0, stream>>>(qb, kb, vtb, mask, 0, csum, H, 0);
        tailcopy<<<dim3(64), 256, 0, stream>>>((const us8*)(H + (size_t)8064 * 1024),
                                               (us8*)hcopy);
        for (int i = 0; i < 6; i++)
            gemm_mfma<0, 1><<<dim3(8, casc[i][1]), 256, 0, stream>>>(
                H, wob, wob, wob, b_out, b_out, b_out, nullptr, nullptr,
                nullptr, outp, x, 0, casc[i][0], 0);
        gemm_mfma<0, 1><<<dim3(8, 1), 256, 0, stream>>>(
            hcopy, wob, wob, wob, b_out, b_out, b_out, nullptr, nullptr,
            nullptr, outp, x, 0, 8064, 8064);
    } else {
        // compact path: <= 6.07 MB ws (proven in R4)
        ushort_t* qb  = (ushort_t*)ws;            // 2 MB
        ushort_t* kb  = (ushort_t*)(ws + 2 * MB); // 2 MB
        ushort_t* vtb = (ushort_t*)(ws + 4 * MB); // 2 MB
        float* csum   = (float*)(ws + 6 * MB);    // 64 KB
        for (int g = 0; g < 8; g++) {
            gemm_mfma<1, 0><<<dim3(8, 8, 3), 256, 0, stream>>>(
                xn + (size_t)g * MB, wq, wk, wv, bq, bk, bv, qb, kb, vtb,
                nullptr, nullptr, 0, 0, 0);
            colstats_mfma<<<dim3(16, 16), 256, 0, stream>>>(qb, kb, mask,
                                                            g * 1024, csum);
            pv_mfma<<<dim3(16, 16), 256, 0, stream>>>(qb, kb, vtb, mask,
                                                      g * 1024, csum, H, g * 1024);
        }
        tailcopy<<<dim3(64), 256, 0, stream>>>((const us8*)(H + (size_t)8064 * 1024),
                                               (us8*)hcopy);
        for (int i = 0; i < 6; i++)
            gemm_mfma<1, 1><<<dim3(8, casc[i][1]), 256, 0, stream>>>(
                H, w_out, w_out, w_out, b_out, b_out, b_out, nullptr, nullptr,
                nullptr, outp, x, 0, casc[i][0], 0);
        gemm_mfma<1, 1><<<dim3(8, 1), 256, 0, stream>>>(
            hcopy, w_out, w_out, w_out, b_out, b_out, b_out, nullptr, nullptr,
            nullptr, outp, x, 0, 8064, 8064);
    }
}

// Round 7
// 392.500 us; speedup vs baseline: 33.1201x; 1.2657x over previous
//
#include <hip/hip_runtime.h>

// B=8, S=1024, H=16, DK=64, D=1024. Inputs/outputs fp32. Internal bf16 MFMA.
// Q is pre-scaled by log2(e)/8 in the QKV epilogue, so QK^T emits
// score*log2e/8 and softmax exps are single v_exp_f32 (exp2) ops.
// Masking is additive (-1e9 pre-exp; exp2(-1e9)=0).
// Big-ws path: out-proj -> ws fp32, then one 32MB D2D memcpy (no cascade).

typedef unsigned short ushort_t;
typedef unsigned short us4 __attribute__((ext_vector_type(4)));
typedef unsigned short us8 __attribute__((ext_vector_type(8)));
typedef __bf16 bf16x8 __attribute__((ext_vector_type(8)));
typedef float f32x4 __attribute__((ext_vector_type(4)));

#define QSCALE 0.18033688011112042f  // log2(e)/8
#define LOG2E 1.4426950408889634f
#define MNEG (-1.0e9f)

__device__ __forceinline__ ushort_t f2bf(float f) {
    unsigned int u = __float_as_uint(f);
    return (ushort_t)((u + 0x7fffu + ((u >> 16) & 1u)) >> 16);  // RTNE
}

// async global->LDS, 16B/lane; LDS dst = wave-uniform base + lane*16
#define GLDS(gp, lp)                                                        \
    __builtin_amdgcn_global_load_lds(                                       \
        (const __attribute__((address_space(1))) unsigned int*)(gp),        \
        (__attribute__((address_space(3))) unsigned int*)(lp), 16, 0, 0)

#define MFMA(a, b, c) __builtin_amdgcn_mfma_f32_16x16x32_bf16((a), (b), (c), 0, 0, 0)

// ---------------- LayerNorm: x fp32 [8192][1024] -> xn bf16 ----------------
__global__ __launch_bounds__(256) void ln_kernel(const float* __restrict__ x,
                                                 ushort_t* __restrict__ xn) {
    int row = blockIdx.x, tid = threadIdx.x;
    float4 v = ((const float4*)(x + (size_t)row * 1024))[tid];
    float s = v.x + v.y + v.z + v.w;
    __shared__ float red[8];
    for (int o = 32; o > 0; o >>= 1) s += __shfl_down(s, o);
    int wave = tid >> 6, lane = tid & 63;
    if (lane == 0) red[wave] = s;
    __syncthreads();
    float mu = (red[0] + red[1] + red[2] + red[3]) * (1.0f / 1024.0f);
    float d0 = v.x - mu, d1 = v.y - mu, d2 = v.z - mu, d3 = v.w - mu;
    float q = d0 * d0 + d1 * d1 + d2 * d2 + d3 * d3;
    for (int o = 32; o > 0; o >>= 1) q += __shfl_down(q, o);
    if (lane == 0) red[wave + 4] = q;
    __syncthreads();
    float var = (red[4] + red[5] + red[6] + red[7]) * (1.0f / 1024.0f);
    float rs = rsqrtf(var + 1e-5f);
    us4 ov;
    ov[0] = f2bf(d0 * rs); ov[1] = f2bf(d1 * rs);
    ov[2] = f2bf(d2 * rs); ov[3] = f2bf(d3 * rs);
    ((us4*)(xn + (size_t)row * 1024))[tid] = ov;
}

// ---------------- fp32 -> bf16 convert (1M elements) -----------------------
__global__ __launch_bounds__(256) void wconv(const float* __restrict__ src,
                                             ushort_t* __restrict__ dst) {
    size_t i = ((size_t)blockIdx.x * 256 + threadIdx.x) * 4;
    float4 f = *(const float4*)(src + i);
    us4 o;
    o[0] = f2bf(f.x); o[1] = f2bf(f.y); o[2] = f2bf(f.z); o[3] = f2bf(f.w);
    *(us4*)(dst + i) = o;
}

// ------------- bf16 tail copy: 128 rows (compact path only) ----------------
__global__ __launch_bounds__(256) void tailcopy(const us8* __restrict__ src,
                                                us8* __restrict__ dst) {
    size_t i = (size_t)blockIdx.x * 256 + threadIdx.x;  // 16384 us8
    dst[i] = src[i];
}

// --------- MFMA bt-GEMM: C[r][n] = sum_k A[r][k] * B[n][k] + bias[n] -------
// BMODE 0: B bf16 (async staged); 1: B fp32 (VALU convert staged)
// OMODE 0: qkv epilogue (bf16 scatter; wsel picks q/k/vt; q pre-scaled)
// OMODE 1: fp32 out + residual
template <int BMODE, int OMODE>
__global__ __launch_bounds__(256) void gemm_mfma(
    const ushort_t* __restrict__ A, const void* __restrict__ Bq,
    const void* __restrict__ Bk, const void* __restrict__ Bv,
    const float* __restrict__ biasq, const float* __restrict__ biask,
    const float* __restrict__ biasv, ushort_t* __restrict__ oq,
    ushort_t* __restrict__ ok, ushort_t* __restrict__ ovt,
    float* __restrict__ ofp, const float* __restrict__ resx, int batched,
    int r0base, int aoff) {
    __shared__ ushort_t As[128 * 32] __attribute__((aligned(16)));
    __shared__ ushort_t Bs[128 * 32] __attribute__((aligned(16)));
    int tid = threadIdx.x, w = tid >> 6, lane = tid & 63;
    int quad = lane >> 4, l15 = lane & 15;
    int wm = w & 1, wn = w >> 1;
    int n0 = blockIdx.x * 128;
    int r0 = r0base + blockIdx.y * 128;
    int wsel = blockIdx.z;
    const void* Bp = (wsel == 0) ? Bq : (wsel == 1) ? Bk : Bv;
    const float* biasp = (wsel == 0) ? biasq : (wsel == 1) ? biask : biasv;
    const float qscale = (OMODE == 0 && wsel == 0) ? QSCALE : 1.0f;

    f32x4 acc[4][4];
#pragma unroll
    for (int i = 0; i < 4; i++)
#pragma unroll
        for (int j = 0; j < 4; j++) acc[i][j] = (f32x4){0.f, 0.f, 0.f, 0.f};

    for (int k0 = 0; k0 < 1024; k0 += 32) {
        __syncthreads();
#pragma unroll
        for (int ii = 0; ii < 2; ii++) {  // A tile 128x32 (8KB)
            int li = (w * 2 + ii) * 64 + lane;
            int row = li >> 2, kc = li & 3;
            GLDS(A + (size_t)(r0 + row - aoff) * 1024 + k0 + kc * 8,
                 &As[(w * 2 + ii) * 512]);
        }
        if (BMODE == 0) {
#pragma unroll
            for (int ii = 0; ii < 2; ii++) {
                int li = (w * 2 + ii) * 64 + lane;
                int row = li >> 2, kc = li & 3;
                GLDS((const ushort_t*)Bp + (size_t)(n0 + row) * 1024 + k0 + kc * 8,
                     &Bs[(w * 2 + ii) * 512]);
            }
        } else {
            int row = tid >> 1, half = tid & 1;
            const float* gb =
                (const float*)Bp + (size_t)(n0 + row) * 1024 + k0 + half * 16;
            float4 f0 = *(const float4*)gb;
            float4 f1 = *(const float4*)(gb + 4);
            float4 f2 = *(const float4*)(gb + 8);
            float4 f3 = *(const float4*)(gb + 12);
            us8 p0, p1;
            p0[0] = f2bf(f0.x); p0[1] = f2bf(f0.y); p0[2] = f2bf(f0.z); p0[3] = f2bf(f0.w);
            p0[4] = f2bf(f1.x); p0[5] = f2bf(f1.y); p0[6] = f2bf(f1.z); p0[7] = f2bf(f1.w);
            p1[0] = f2bf(f2.x); p1[1] = f2bf(f2.y); p1[2] = f2bf(f2.z); p1[3] = f2bf(f2.w);
            p1[4] = f2bf(f3.x); p1[5] = f2bf(f3.y); p1[6] = f2bf(f3.z); p1[7] = f2bf(f3.w);
            *(us8*)&Bs[row * 32 + half * 16] = p0;
            *(us8*)&Bs[row * 32 + half * 16 + 8] = p1;
        }
        __syncthreads();
        bf16x8 a[4], b[4];
#pragma unroll
        for (int i = 0; i < 4; i++)
            a[i] = *(const bf16x8*)&As[(wm * 64 + i * 16 + l15) * 32 + quad * 8];
#pragma unroll
        for (int j = 0; j < 4; j++)
            b[j] = *(const bf16x8*)&Bs[(wn * 64 + j * 16 + l15) * 32 + quad * 8];
#pragma unroll
        for (int i = 0; i < 4; i++)
#pragma unroll
            for (int j = 0; j < 4; j++) acc[i][j] = MFMA(a[i], b[j], acc[i][j]);
    }
    // epilogue; C layout: col=l15, row=quad*4+v
#pragma unroll
    for (int j = 0; j < 4; j++) {
        int n = n0 + wn * 64 + j * 16 + l15;
        float bj = biasp[n];
        if (OMODE == 0) {
            int h = n >> 6, kk = n & 63;
#pragma unroll
            for (int i = 0; i < 4; i++) {
#pragma unroll
                for (int v = 0; v < 4; v++) {
                    int r = r0 + wm * 64 + i * 16 + quad * 4 + v;
                    int bb = batched ? (r >> 10) : 0;
                    int s = r & 1023;
                    ushort_t val = f2bf((acc[i][j][v] + bj) * qscale);
                    if (wsel < 2) {
                        ushort_t* op = (wsel == 0) ? oq : ok;
                        op[((size_t)(bb * 16 + h) * 1024 + s) * 64 + kk] = val;
                    } else {
                        ovt[((size_t)(bb * 16 + h) * 64 + kk) * 1024 + s] = val;
                    }
                }
            }
        } else {
#pragma unroll
            for (int i = 0; i < 4; i++) {
#pragma unroll
                for (int v = 0; v < 4; v++) {
                    int r = r0 + wm * 64 + i * 16 + quad * 4 + v;
                    size_t idx = (size_t)r * 1024 + n;
                    ofp[idx] = acc[i][j][v] + bj + resx[idx];
                }
            }
        }
    }
}

// --- colsum[bh][t] = sum_s exp(masked score) ; MFMA 64x64 tiles ------------
__global__ __launch_bounds__(256) void colstats_mfma(
    const ushort_t* __restrict__ qb, const ushort_t* __restrict__ kb,
    const float* __restrict__ mask, int moff, float* __restrict__ colsum) {
    __shared__ ushort_t Ks[4096] __attribute__((aligned(16)));  // [2][64][32]
    __shared__ ushort_t Qs[4096] __attribute__((aligned(16)));
    __shared__ float mk[64], mq[64], red[4][64];
    int tid = threadIdx.x, w = tid >> 6, lane = tid & 63;
    int quad = lane >> 4, l15 = lane & 15;
    int by = blockIdx.y;
    size_t qoff = (size_t)by * 65536;
    int coff = by * 1024;
    int mb = moff + (by >> 4) * 1024;
    int t0 = blockIdx.x * 64;
#pragma unroll
    for (int ii = 0; ii < 2; ii++) {
        int qq = w * 2 + ii, half = qq >> 2, sub = qq & 3;
        int li = sub * 64 + lane, row = li >> 2, seg = li & 3;
        GLDS(kb + qoff + (size_t)(t0 + row) * 64 + half * 32 + seg * 8,
             &Ks[half * 2048 + sub * 512]);
    }
    if (tid < 64) mk[tid] = mask[mb + t0 + tid];
    __syncthreads();
    float amk[4];
#pragma unroll
    for (int j = 0; j < 4; j++) amk[j] = (mk[j * 16 + l15] > 0.f) ? 0.f : MNEG;
    float colacc[4] = {0.f, 0.f, 0.f, 0.f};
    for (int s0 = 0; s0 < 1024; s0 += 64) {
        __syncthreads();
#pragma unroll
        for (int ii = 0; ii < 2; ii++) {
            int qq = w * 2 + ii, half = qq >> 2, sub = qq & 3;
            int li = sub * 64 + lane, row = li >> 2, seg = li & 3;
            GLDS(qb + qoff + (size_t)(s0 + row) * 64 + half * 32 + seg * 8,
                 &Qs[half * 2048 + sub * 512]);
        }
        if (tid < 64) mq[tid] = mask[mb + s0 + tid];
        __syncthreads();
        float amq[4];
#pragma unroll
        for (int v = 0; v < 4; v++)
            amq[v] = (mq[w * 16 + quad * 4 + v] > 0.f) ? 0.f : MNEG;
        bf16x8 a0 = *(const bf16x8*)&Qs[(w * 16 + l15) * 32 + quad * 8];
        bf16x8 a1 = *(const bf16x8*)&Qs[2048 + (w * 16 + l15) * 32 + quad * 8];
#pragma unroll
        for (int j = 0; j < 4; j++) {
            bf16x8 b0 = *(const bf16x8*)&Ks[(j * 16 + l15) * 32 + quad * 8];
            bf16x8 b1 = *(const bf16x8*)&Ks[2048 + (j * 16 + l15) * 32 + quad * 8];
            f32x4 sc = (f32x4){0.f, 0.f, 0.f, 0.f};
            sc = MFMA(a0, b0, sc);
            sc = MFMA(a1, b1, sc);
#pragma unroll
            for (int v = 0; v < 4; v++)
                colacc[j] += exp2f(sc[v] + amq[v] + amk[j]);
        }
    }
#pragma unroll
    for (int j = 0; j < 4; j++) {
        float vv = colacc[j];
        vv += __shfl_down(vv, 32);
        vv += __shfl_down(vv, 16);
        if (quad == 0) red[w][j * 16 + l15] = vv;
    }
    __syncthreads();
    if (tid < 64)
        colsum[coff + t0 + tid] = red[0][tid] + red[1][tid] + red[2][tid] + red[3][tid];
}

// --- double softmax + PV (MFMA); heads bf16, single base -------------------
__global__ __launch_bounds__(256) void pv_mfma(
    const ushort_t* __restrict__ qb, const ushort_t* __restrict__ kb,
    const ushort_t* __restrict__ vtb, const float* __restrict__ mask, int moff,
    const float* __restrict__ colsum, ushort_t* __restrict__ H, int hbase) {
    __shared__ ushort_t Qs[4096] __attribute__((aligned(16)));
    __shared__ ushort_t Ks[4096] __attribute__((aligned(16)));
    __shared__ ushort_t Vt[4096] __attribute__((aligned(16)));  // [2][64dk][32t]
    __shared__ ushort_t E[64 * 72] __attribute__((aligned(16)));
    __shared__ float mk[64], mq[64], ics[64];
    int tid = threadIdx.x, w = tid >> 6, lane = tid & 63;
    int quad = lane >> 4, l15 = lane & 15;
    int by = blockIdx.y;
    size_t qoff = (size_t)by * 65536;
    int coff = by * 1024;
    int mb = moff + (by >> 4) * 1024;
    int h = by & 15;
    int s0 = blockIdx.x * 64;
#pragma unroll
    for (int ii = 0; ii < 2; ii++) {
        int qq = w * 2 + ii, half = qq >> 2, sub = qq & 3;
        int li = sub * 64 + lane, row = li >> 2, seg = li & 3;
        GLDS(qb + qoff + (size_t)(s0 + row) * 64 + half * 32 + seg * 8,
             &Qs[half * 2048 + sub * 512]);
    }
    if (tid < 64) mq[tid] = mask[mb + s0 + tid];
    __syncthreads();
    float amq[4];
#pragma unroll
    for (int v = 0; v < 4; v++)
        amq[v] = (mq[w * 16 + quad * 4 + v] > 0.f) ? 0.f : MNEG;
    bf16x8 ones;
#pragma unroll
    for (int e = 0; e < 8; e++) ones[e] = (__bf16)1.0f;
    f32x4 acc_o[4], acc_rs = (f32x4){0.f, 0.f, 0.f, 0.f};
#pragma unroll
    for (int j = 0; j < 4; j++) acc_o[j] = (f32x4){0.f, 0.f, 0.f, 0.f};
    for (int t0 = 0; t0 < 1024; t0 += 64) {
        __syncthreads();
#pragma unroll
        for (int ii = 0; ii < 2; ii++) {
            int qq = w * 2 + ii, half = qq >> 2, sub = qq & 3;
            int li = sub * 64 + lane, row = li >> 2, seg = li & 3;
            GLDS(kb + qoff + (size_t)(t0 + row) * 64 + half * 32 + seg * 8,
                 &Ks[half * 2048 + sub * 512]);
            GLDS(vtb + qoff + (size_t)row * 1024 + t0 + half * 32 + seg * 8,
                 &Vt[half * 2048 + sub * 512]);
        }
        if (tid < 64) {
            mk[tid] = mask[mb + t0 + tid];
            float cs = colsum[coff + t0 + tid];
            ics[tid] = (cs > 0.f) ? LOG2E / cs : 0.f;
        }
        __syncthreads();
        bf16x8 a0 = *(const bf16x8*)&Qs[(w * 16 + l15) * 32 + quad * 8];
        bf16x8 a1 = *(const bf16x8*)&Qs[2048 + (w * 16 + l15) * 32 + quad * 8];
#pragma unroll
        for (int j = 0; j < 4; j++) {
            bf16x8 b0 = *(const bf16x8*)&Ks[(j * 16 + l15) * 32 + quad * 8];
            bf16x8 b1 = *(const bf16x8*)&Ks[2048 + (j * 16 + l15) * 32 + quad * 8];
            f32x4 sc = (f32x4){0.f, 0.f, 0.f, 0.f};
            sc = MFMA(a0, b0, sc);
            sc = MFMA(a1, b1, sc);
            int tcol = j * 16 + l15;
            float icv = ics[tcol];
            float aj = (mk[tcol] > 0.f) ? 0.f : MNEG;
            float am[4];
#pragma unroll
            for (int v = 0; v < 4; v++) am[v] = amq[v] + aj;
#pragma unroll
            for (int v = 0; v < 4; v++) {
                float e1 = exp2f(sc[v]);                 // exp(score/8)
                float e2 = exp2f(fmaf(e1, icv, am[v]));  // exp(attn1) or 0
                int sl = w * 16 + quad * 4 + v;
                E[sl * 72 + tcol] = (ushort_t)(__float_as_uint(e2) >> 16);
            }
        }
        // PV: each wave reads only its own 16-row E strip (same-wave LDS order)
        bf16x8 ea0 = *(const bf16x8*)&E[(w * 16 + l15) * 72 + quad * 8];
        bf16x8 ea1 = *(const bf16x8*)&E[(w * 16 + l15) * 72 + 32 + quad * 8];
#pragma unroll
        for (int j = 0; j < 4; j++) {
            bf16x8 b0 = *(const bf16x8*)&Vt[(j * 16 + l15) * 32 + quad * 8];
            bf16x8 b1 = *(const bf16x8*)&Vt[2048 + (j * 16 + l15) * 32 + quad * 8];
            acc_o[j] = MFMA(ea0, b0, acc_o[j]);
            acc_o[j] = MFMA(ea1, b1, acc_o[j]);
        }
        acc_rs = MFMA(ea0, ones, acc_rs);
        acc_rs = MFMA(ea1, ones, acc_rs);
    }
#pragma unroll
    for (int v = 0; v < 4; v++) {
        int sl = w * 16 + quad * 4 + v;
        int hr = hbase + (by >> 4) * 1024 + s0 + sl;
        ushort_t* hp = H + (size_t)hr * 1024;
        float inv = 1.0f / fmaxf(acc_rs[v], 1e-30f);
#pragma unroll
        for (int j = 0; j < 4; j++)
            hp[h * 64 + j * 16 + l15] = f2bf(acc_o[j][v] * inv);
    }
}

extern "C" void kernel_launch(void* const* d_in, const int* in_sizes, int n_in,
                              void* d_out, int out_size, void* d_ws, size_t ws_size,
                              hipStream_t stream) {
    const float* x     = (const float*)d_in[0];
    const float* mask  = (const float*)d_in[1];
    const float* wq    = (const float*)d_in[2];
    const float* bq    = (const float*)d_in[3];
    const float* wk    = (const float*)d_in[4];
    const float* bk    = (const float*)d_in[5];
    const float* wv    = (const float*)d_in[6];
    const float* bv    = (const float*)d_in[7];
    const float* w_out = (const float*)d_in[8];
    const float* b_out = (const float*)d_in[9];
    float* outp = (float*)d_out;

    const size_t MB = 1024 * 1024;
    ushort_t* xn = (ushort_t*)d_out;             // bytes [0,16MB), dead after qkv
    ushort_t* H  = (ushort_t*)d_out + 8 * MB;    // heads bf16, bytes [16MB,32MB)
    char* ws = (char*)d_ws;

    ln_kernel<<<dim3(8192), 256, 0, stream>>>(x, xn);

    if (ws_size >= 58 * MB) {
        ushort_t* qb  = (ushort_t*)ws;             // 16 MB (dead after pv)
        ushort_t* kb  = (ushort_t*)(ws + 16 * MB); // 16 MB (dead after pv)
        ushort_t* vtb = (ushort_t*)(ws + 32 * MB); // 16 MB
        float* csum   = (float*)(ws + 48 * MB);    // 512 KB
        ushort_t* wqb = (ushort_t*)(ws + 49 * MB);
        ushort_t* wkb = (ushort_t*)(ws + 51 * MB);
        ushort_t* wvb = (ushort_t*)(ws + 53 * MB);
        ushort_t* wob = (ushort_t*)(ws + 55 * MB);
        float* ofull  = (float*)ws;                // 32 MB fp32 out (aliases qb/kb)
        wconv<<<dim3(1024), 256, 0, stream>>>(wq, wqb);
        wconv<<<dim3(1024), 256, 0, stream>>>(wk, wkb);
        wconv<<<dim3(1024), 256, 0, stream>>>(wv, wvb);
        wconv<<<dim3(1024), 256, 0, stream>>>(w_out, wob);
        gemm_mfma<0, 0><<<dim3(8, 64, 3), 256, 0, stream>>>(
            xn, wqb, wkb, wvb, bq, bk, bv, qb, kb, vtb, nullptr, nullptr, 1, 0, 0);
        colstats_mfma<<<dim3(16, 128), 256, 0, stream>>>(qb, kb, mask, 0, csum);
        pv_mfma<<<dim3(16, 128), 256, 0, stream>>>(qb, kb, vtb, mask, 0, csum, H, 0);
        gemm_mfma<0, 1><<<dim3(8, 64), 256, 0, stream>>>(
            H, wob, wob, wob, b_out, b_out, b_out, nullptr, nullptr, nullptr,
            ofull, x, 0, 0, 0);
        hipMemcpyAsync(d_out, ofull, 32 * MB, hipMemcpyDeviceToDevice, stream);
    } else {
        // compact path: <= 6.07 MB ws; in-place cascade out-proj (R4/R6-proven)
        ushort_t* qb  = (ushort_t*)ws;            // 2 MB
        ushort_t* kb  = (ushort_t*)(ws + 2 * MB); // 2 MB
        ushort_t* vtb = (ushort_t*)(ws + 4 * MB); // 2 MB
        float* csum   = (float*)(ws + 6 * MB);    // 64 KB
        ushort_t* hcopy = (ushort_t*)ws;          // 256KB tail copy (qb dead)
        const int casc[6][2] = {{0, 32},   {4096, 16}, {6144, 8},
                                {7168, 4}, {7680, 2},  {7936, 1}};
        for (int g = 0; g < 8; g++) {
            gemm_mfma<1, 0><<<dim3(8, 8, 3), 256, 0, stream>>>(
                xn + (size_t)g * MB, wq, wk, wv, bq, bk, bv, qb, kb, vtb,
                nullptr, nullptr, 0, 0, 0);
            colstats_mfma<<<dim3(16, 16), 256, 0, stream>>>(qb, kb, mask,
                                                            g * 1024, csum);
            pv_mfma<<<dim3(16, 16), 256, 0, stream>>>(qb, kb, vtb, mask,
                                                      g * 1024, csum, H, g * 1024);
        }
        tailcopy<<<dim3(64), 256, 0, stream>>>((const us8*)(H + (size_t)8064 * 1024),
                                               (us8*)hcopy);
        for (int i = 0; i < 6; i++)
            gemm_mfma<1, 1><<<dim3(8, casc[i][1]), 256, 0, stream>>>(
                H, w_out, w_out, w_out, b_out, b_out, b_out, nullptr, nullptr,
                nullptr, outp, x, 0, casc[i][0], 0);
        gemm_mfma<1, 1><<<dim3(8, 1), 256, 0, stream>>>(
            hcopy, w_out, w_out, w_out, b_out, b_out, b_out, nullptr, nullptr,
            nullptr, outp, x, 0, 8064, 8064);
    }
}

// Round 8
// 353.253 us; speedup vs baseline: 36.7997x; 1.1111x over previous
//
#include <hip/hip_runtime.h>

// B=8, S=1024, H=16, DK=64, D=1024. Inputs/outputs fp32. Internal bf16 MFMA.
// Q pre-scaled by log2(e)/8 so QK^T emits score*log2e/8; exps are raw
// v_exp_f32 (__builtin_amdgcn_exp2f); masking additive (-1e9 pre-exp).
// All GLDS-staged LDS tiles are XOR-swizzled: position (row,c4) holds global
// chunk c4 ^ ((row>>1)&3); fragment reads use chunk quad ^ ((l15>>1)&3)
// (per-thread constant) -> 8-way bank conflicts become 2-way (free).

typedef unsigned short ushort_t;
typedef unsigned short us4 __attribute__((ext_vector_type(4)));
typedef unsigned short us8 __attribute__((ext_vector_type(8)));
typedef __bf16 bf16x8 __attribute__((ext_vector_type(8)));
typedef float f32x4 __attribute__((ext_vector_type(4)));

#define QSCALE 0.18033688011112042f  // log2(e)/8
#define LOG2E 1.4426950408889634f
#define MNEG (-1.0e9f)
#define EXP2(x) __builtin_amdgcn_exp2f(x)

__device__ __forceinline__ ushort_t f2bf(float f) {
    unsigned int u = __float_as_uint(f);
    return (ushort_t)((u + 0x7fffu + ((u >> 16) & 1u)) >> 16);  // RTNE
}

// async global->LDS, 16B/lane; LDS dst = wave-uniform base + lane*16
#define GLDS(gp, lp)                                                        \
    __builtin_amdgcn_global_load_lds(                                       \
        (const __attribute__((address_space(1))) unsigned int*)(gp),        \
        (__attribute__((address_space(3))) unsigned int*)(lp), 16, 0, 0)

#define MFMA(a, b, c) __builtin_amdgcn_mfma_f32_16x16x32_bf16((a), (b), (c), 0, 0, 0)

// ---------------- LayerNorm: x fp32 [8192][1024] -> xn bf16 ----------------
__global__ __launch_bounds__(256) void ln_kernel(const float* __restrict__ x,
                                                 ushort_t* __restrict__ xn) {
    int row = blockIdx.x, tid = threadIdx.x;
    float4 v = ((const float4*)(x + (size_t)row * 1024))[tid];
    float s = v.x + v.y + v.z + v.w;
    __shared__ float red[8];
    for (int o = 32; o > 0; o >>= 1) s += __shfl_down(s, o);
    int wave = tid >> 6, lane = tid & 63;
    if (lane == 0) red[wave] = s;
    __syncthreads();
    float mu = (red[0] + red[1] + red[2] + red[3]) * (1.0f / 1024.0f);
    float d0 = v.x - mu, d1 = v.y - mu, d2 = v.z - mu, d3 = v.w - mu;
    float q = d0 * d0 + d1 * d1 + d2 * d2 + d3 * d3;
    for (int o = 32; o > 0; o >>= 1) q += __shfl_down(q, o);
    if (lane == 0) red[wave + 4] = q;
    __syncthreads();
    float var = (red[4] + red[5] + red[6] + red[7]) * (1.0f / 1024.0f);
    float rs = rsqrtf(var + 1e-5f);
    us4 ov;
    ov[0] = f2bf(d0 * rs); ov[1] = f2bf(d1 * rs);
    ov[2] = f2bf(d2 * rs); ov[3] = f2bf(d3 * rs);
    ((us4*)(xn + (size_t)row * 1024))[tid] = ov;
}

// ---------------- fp32 -> bf16 convert (1M elements) -----------------------
__global__ __launch_bounds__(256) void wconv(const float* __restrict__ src,
                                             ushort_t* __restrict__ dst) {
    size_t i = ((size_t)blockIdx.x * 256 + threadIdx.x) * 4;
    float4 f = *(const float4*)(src + i);
    us4 o;
    o[0] = f2bf(f.x); o[1] = f2bf(f.y); o[2] = f2bf(f.z); o[3] = f2bf(f.w);
    *(us4*)(dst + i) = o;
}

// ------------- bf16 tail copy: 128 rows (compact path only) ----------------
__global__ __launch_bounds__(256) void tailcopy(const us8* __restrict__ src,
                                                us8* __restrict__ dst) {
    size_t i = (size_t)blockIdx.x * 256 + threadIdx.x;  // 16384 us8
    dst[i] = src[i];
}

// --------- MFMA bt-GEMM: C[r][n] = sum_k A[r][k] * B[n][k] + bias[n] -------
// BMODE 0: B bf16 (async staged); 1: B fp32 (VALU convert staged)
// OMODE 0: qkv epilogue (bf16 scatter; wsel picks q/k/vt; q pre-scaled)
// OMODE 1: fp32 out + residual
template <int BMODE, int OMODE>
__global__ __launch_bounds__(256) void gemm_mfma(
    const ushort_t* __restrict__ A, const void* __restrict__ Bq,
    const void* __restrict__ Bk, const void* __restrict__ Bv,
    const float* __restrict__ biasq, const float* __restrict__ biask,
    const float* __restrict__ biasv, ushort_t* __restrict__ oq,
    ushort_t* __restrict__ ok, ushort_t* __restrict__ ovt,
    float* __restrict__ ofp, const float* __restrict__ resx, int batched,
    int r0base, int aoff) {
    __shared__ ushort_t As[128 * 32] __attribute__((aligned(16)));
    __shared__ ushort_t Bs[128 * 32] __attribute__((aligned(16)));
    int tid = threadIdx.x, w = tid >> 6, lane = tid & 63;
    int quad = lane >> 4, l15 = lane & 15;
    int wm = w & 1, wn = w >> 1;
    int csw = (quad ^ ((l15 >> 1) & 3)) * 8;  // swizzled chunk offset
    int n0 = blockIdx.x * 128;
    int r0 = r0base + blockIdx.y * 128;
    int wsel = blockIdx.z;
    const void* Bp = (wsel == 0) ? Bq : (wsel == 1) ? Bk : Bv;
    const float* biasp = (wsel == 0) ? biasq : (wsel == 1) ? biask : biasv;
    const float qscale = (OMODE == 0 && wsel == 0) ? QSCALE : 1.0f;

    f32x4 acc[4][4];
#pragma unroll
    for (int i = 0; i < 4; i++)
#pragma unroll
        for (int j = 0; j < 4; j++) acc[i][j] = (f32x4){0.f, 0.f, 0.f, 0.f};

    for (int k0 = 0; k0 < 1024; k0 += 32) {
        __syncthreads();
#pragma unroll
        for (int ii = 0; ii < 2; ii++) {  // A tile 128x32 (8KB)
            int li = (w * 2 + ii) * 64 + lane;
            int row = li >> 2, kc = li & 3;
            int sk = kc ^ ((row >> 1) & 3);
            GLDS(A + (size_t)(r0 + row - aoff) * 1024 + k0 + sk * 8,
                 &As[(w * 2 + ii) * 512]);
        }
        if (BMODE == 0) {
#pragma unroll
            for (int ii = 0; ii < 2; ii++) {
                int li = (w * 2 + ii) * 64 + lane;
                int row = li >> 2, kc = li & 3;
                int sk = kc ^ ((row >> 1) & 3);
                GLDS((const ushort_t*)Bp + (size_t)(n0 + row) * 1024 + k0 + sk * 8,
                     &Bs[(w * 2 + ii) * 512]);
            }
        } else {
            int row = tid >> 1, half = tid & 1;
            int sw = (row >> 1) & 3;
            const float* gb =
                (const float*)Bp + (size_t)(n0 + row) * 1024 + k0 + half * 16;
            float4 f0 = *(const float4*)gb;
            float4 f1 = *(const float4*)(gb + 4);
            float4 f2 = *(const float4*)(gb + 8);
            float4 f3 = *(const float4*)(gb + 12);
            us8 p0, p1;
            p0[0] = f2bf(f0.x); p0[1] = f2bf(f0.y); p0[2] = f2bf(f0.z); p0[3] = f2bf(f0.w);
            p0[4] = f2bf(f1.x); p0[5] = f2bf(f1.y); p0[6] = f2bf(f1.z); p0[7] = f2bf(f1.w);
            p1[0] = f2bf(f2.x); p1[1] = f2bf(f2.y); p1[2] = f2bf(f2.z); p1[3] = f2bf(f2.w);
            p1[4] = f2bf(f3.x); p1[5] = f2bf(f3.y); p1[6] = f2bf(f3.z); p1[7] = f2bf(f3.w);
            *(us8*)&Bs[row * 32 + ((half * 2) ^ sw) * 8] = p0;
            *(us8*)&Bs[row * 32 + ((half * 2 + 1) ^ sw) * 8] = p1;
        }
        __syncthreads();
        bf16x8 a[4], b[4];
#pragma unroll
        for (int i = 0; i < 4; i++)
            a[i] = *(const bf16x8*)&As[(wm * 64 + i * 16 + l15) * 32 + csw];
#pragma unroll
        for (int j = 0; j < 4; j++)
            b[j] = *(const bf16x8*)&Bs[(wn * 64 + j * 16 + l15) * 32 + csw];
#pragma unroll
        for (int i = 0; i < 4; i++)
#pragma unroll
            for (int j = 0; j < 4; j++) acc[i][j] = MFMA(a[i], b[j], acc[i][j]);
    }
    // epilogue; C layout: col=l15, row=quad*4+v
#pragma unroll
    for (int j = 0; j < 4; j++) {
        int n = n0 + wn * 64 + j * 16 + l15;
        float bj = biasp[n];
        if (OMODE == 0) {
            int h = n >> 6, kk = n & 63;
#pragma unroll
            for (int i = 0; i < 4; i++) {
#pragma unroll
                for (int v = 0; v < 4; v++) {
                    int r = r0 + wm * 64 + i * 16 + quad * 4 + v;
                    int bb = batched ? (r >> 10) : 0;
                    int s = r & 1023;
                    ushort_t val = f2bf((acc[i][j][v] + bj) * qscale);
                    if (wsel < 2) {
                        ushort_t* op = (wsel == 0) ? oq : ok;
                        op[((size_t)(bb * 16 + h) * 1024 + s) * 64 + kk] = val;
                    } else {
                        ovt[((size_t)(bb * 16 + h) * 64 + kk) * 1024 + s] = val;
                    }
                }
            }
        } else {
#pragma unroll
            for (int i = 0; i < 4; i++) {
#pragma unroll
                for (int v = 0; v < 4; v++) {
                    int r = r0 + wm * 64 + i * 16 + quad * 4 + v;
                    size_t idx = (size_t)r * 1024 + n;
                    ofp[idx] = acc[i][j][v] + bj + resx[idx];
                }
            }
        }
    }
}

// --- colsum[bh][t] = sum_s exp(masked score) ; MFMA 64x64 tiles ------------
__global__ __launch_bounds__(256) void colstats_mfma(
    const ushort_t* __restrict__ qb, const ushort_t* __restrict__ kb,
    const float* __restrict__ mask, int moff, float* __restrict__ colsum) {
    __shared__ ushort_t Ks[4096] __attribute__((aligned(16)));  // [2][64][32]
    __shared__ ushort_t Qs[4096] __attribute__((aligned(16)));
    __shared__ float mk[64], mq[64], red[4][64];
    int tid = threadIdx.x, w = tid >> 6, lane = tid & 63;
    int quad = lane >> 4, l15 = lane & 15;
    int csw = (quad ^ ((l15 >> 1) & 3)) * 8;
    int by = blockIdx.y;
    size_t qoff = (size_t)by * 65536;
    int coff = by * 1024;
    int mb = moff + (by >> 4) * 1024;
    int t0 = blockIdx.x * 64;
#pragma unroll
    for (int ii = 0; ii < 2; ii++) {
        int qq = w * 2 + ii, half = qq >> 2, sub = qq & 3;
        int li = sub * 64 + lane, row = li >> 2, seg = li & 3;
        int sk = seg ^ ((row >> 1) & 3);
        GLDS(kb + qoff + (size_t)(t0 + row) * 64 + half * 32 + sk * 8,
             &Ks[half * 2048 + sub * 512]);
    }
    if (tid < 64) mk[tid] = mask[mb + t0 + tid];
    __syncthreads();
    // hoist K fragments (loop-invariant) into registers
    bf16x8 kf0[4], kf1[4];
#pragma unroll
    for (int j = 0; j < 4; j++) {
        kf0[j] = *(const bf16x8*)&Ks[(j * 16 + l15) * 32 + csw];
        kf1[j] = *(const bf16x8*)&Ks[2048 + (j * 16 + l15) * 32 + csw];
    }
    float amk[4];
#pragma unroll
    for (int j = 0; j < 4; j++) amk[j] = (mk[j * 16 + l15] > 0.f) ? 0.f : MNEG;
    float colacc[4] = {0.f, 0.f, 0.f, 0.f};
    for (int s0 = 0; s0 < 1024; s0 += 64) {
        __syncthreads();
#pragma unroll
        for (int ii = 0; ii < 2; ii++) {
            int qq = w * 2 + ii, half = qq >> 2, sub = qq & 3;
            int li = sub * 64 + lane, row = li >> 2, seg = li & 3;
            int sk = seg ^ ((row >> 1) & 3);
            GLDS(qb + qoff + (size_t)(s0 + row) * 64 + half * 32 + sk * 8,
                 &Qs[half * 2048 + sub * 512]);
        }
        if (tid < 64) mq[tid] = mask[mb + s0 + tid];
        __syncthreads();
        float amq[4];
#pragma unroll
        for (int v = 0; v < 4; v++)
            amq[v] = (mq[w * 16 + quad * 4 + v] > 0.f) ? 0.f : MNEG;
        bf16x8 a0 = *(const bf16x8*)&Qs[(w * 16 + l15) * 32 + csw];
        bf16x8 a1 = *(const bf16x8*)&Qs[2048 + (w * 16 + l15) * 32 + csw];
#pragma unroll
        for (int j = 0; j < 4; j++) {
            f32x4 sc = (f32x4){0.f, 0.f, 0.f, 0.f};
            sc = MFMA(a0, kf0[j], sc);
            sc = MFMA(a1, kf1[j], sc);
#pragma unroll
            for (int v = 0; v < 4; v++)
                colacc[j] += EXP2(sc[v] + amq[v] + amk[j]);
        }
    }
#pragma unroll
    for (int j = 0; j < 4; j++) {
        float vv = colacc[j];
        vv += __shfl_down(vv, 32);
        vv += __shfl_down(vv, 16);
        if (quad == 0) red[w][j * 16 + l15] = vv;
    }
    __syncthreads();
    if (tid < 64)
        colsum[coff + t0 + tid] = red[0][tid] + red[1][tid] + red[2][tid] + red[3][tid];
}

// --- double softmax + PV (MFMA); heads bf16, single base -------------------
__global__ __launch_bounds__(256) void pv_mfma(
    const ushort_t* __restrict__ qb, const ushort_t* __restrict__ kb,
    const ushort_t* __restrict__ vtb, const float* __restrict__ mask, int moff,
    const float* __restrict__ colsum, ushort_t* __restrict__ H, int hbase) {
    __shared__ ushort_t Qs[4096] __attribute__((aligned(16)));
    __shared__ ushort_t Ks[4096] __attribute__((aligned(16)));
    __shared__ ushort_t Vt[4096] __attribute__((aligned(16)));  // [2][64dk][32t]
    __shared__ ushort_t E[64 * 72] __attribute__((aligned(16)));
    __shared__ float mk[64], mq[64], ics[64];
    int tid = threadIdx.x, w = tid >> 6, lane = tid & 63;
    int quad = lane >> 4, l15 = lane & 15;
    int csw = (quad ^ ((l15 >> 1) & 3)) * 8;
    int by = blockIdx.y;
    size_t qoff = (size_t)by * 65536;
    int coff = by * 1024;
    int mb = moff + (by >> 4) * 1024;
    int h = by & 15;
    int s0 = blockIdx.x * 64;
#pragma unroll
    for (int ii = 0; ii < 2; ii++) {
        int qq = w * 2 + ii, half = qq >> 2, sub = qq & 3;
        int li = sub * 64 + lane, row = li >> 2, seg = li & 3;
        int sk = seg ^ ((row >> 1) & 3);
        GLDS(qb + qoff + (size_t)(s0 + row) * 64 + half * 32 + sk * 8,
             &Qs[half * 2048 + sub * 512]);
    }
    if (tid < 64) mq[tid] = mask[mb + s0 + tid];
    __syncthreads();
    // hoist Q fragments (loop-invariant)
    bf16x8 a0 = *(const bf16x8*)&Qs[(w * 16 + l15) * 32 + csw];
    bf16x8 a1 = *(const bf16x8*)&Qs[2048 + (w * 16 + l15) * 32 + csw];
    float amq[4];
#pragma unroll
    for (int v = 0; v < 4; v++)
        amq[v] = (mq[w * 16 + quad * 4 + v] > 0.f) ? 0.f : MNEG;
    bf16x8 ones;
#pragma unroll
    for (int e = 0; e < 8; e++) ones[e] = (__bf16)1.0f;
    f32x4 acc_o[4], acc_rs = (f32x4){0.f, 0.f, 0.f, 0.f};
#pragma unroll
    for (int j = 0; j < 4; j++) acc_o[j] = (f32x4){0.f, 0.f, 0.f, 0.f};
    for (int t0 = 0; t0 < 1024; t0 += 64) {
        __syncthreads();
#pragma unroll
        for (int ii = 0; ii < 2; ii++) {
            int qq = w * 2 + ii, half = qq >> 2, sub = qq & 3;
            int li = sub * 64 + lane, row = li >> 2, seg = li & 3;
            int sk = seg ^ ((row >> 1) & 3);
            GLDS(kb + qoff + (size_t)(t0 + row) * 64 + half * 32 + sk * 8,
                 &Ks[half * 2048 + sub * 512]);
            GLDS(vtb + qoff + (size_t)row * 1024 + t0 + half * 32 + sk * 8,
                 &Vt[half * 2048 + sub * 512]);
        }
        if (tid < 64) {
            mk[tid] = mask[mb + t0 + tid];
            float cs = colsum[coff + t0 + tid];
            ics[tid] = (cs > 0.f) ? LOG2E / cs : 0.f;
        }
        __syncthreads();
#pragma unroll
        for (int j = 0; j < 4; j++) {
            bf16x8 b0 = *(const bf16x8*)&Ks[(j * 16 + l15) * 32 + csw];
            bf16x8 b1 = *(const bf16x8*)&Ks[2048 + (j * 16 + l15) * 32 + csw];
            f32x4 sc = (f32x4){0.f, 0.f, 0.f, 0.f};
            sc = MFMA(a0, b0, sc);
            sc = MFMA(a1, b1, sc);
            int tcol = j * 16 + l15;
            float icv = ics[tcol];
            float aj = (mk[tcol] > 0.f) ? 0.f : MNEG;
#pragma unroll
            for (int v = 0; v < 4; v++) {
                float e1 = EXP2(sc[v]);                       // exp(score/8)
                float e2 = EXP2(fmaf(e1, icv, amq[v] + aj));  // exp(attn1) or 0
                int sl = w * 16 + quad * 4 + v;
                E[sl * 72 + tcol] = (ushort_t)(__float_as_uint(e2) >> 16);
            }
        }
        // PV: each wave reads only its own 16-row E strip (same-wave LDS order)
        bf16x8 ea0 = *(const bf16x8*)&E[(w * 16 + l15) * 72 + quad * 8];
        bf16x8 ea1 = *(const bf16x8*)&E[(w * 16 + l15) * 72 + 32 + quad * 8];
#pragma unroll
        for (int j = 0; j < 4; j++) {
            bf16x8 b0 = *(const bf16x8*)&Vt[(j * 16 + l15) * 32 + csw];
            bf16x8 b1 = *(const bf16x8*)&Vt[2048 + (j * 16 + l15) * 32 + csw];
            acc_o[j] = MFMA(ea0, b0, acc_o[j]);
            acc_o[j] = MFMA(ea1, b1, acc_o[j]);
        }
        acc_rs = MFMA(ea0, ones, acc_rs);
        acc_rs = MFMA(ea1, ones, acc_rs);
    }
#pragma unroll
    for (int v = 0; v < 4; v++) {
        int sl = w * 16 + quad * 4 + v;
        int hr = hbase + (by >> 4) * 1024 + s0 + sl;
        ushort_t* hp = H + (size_t)hr * 1024;
        float inv = 1.0f / fmaxf(acc_rs[v], 1e-30f);
#pragma unroll
        for (int j = 0; j < 4; j++)
            hp[h * 64 + j * 16 + l15] = f2bf(acc_o[j][v] * inv);
    }
}

extern "C" void kernel_launch(void* const* d_in, const int* in_sizes, int n_in,
                              void* d_out, int out_size, void* d_ws, size_t ws_size,
                              hipStream_t stream) {
    const float* x     = (const float*)d_in[0];
    const float* mask  = (const float*)d_in[1];
    const float* wq    = (const float*)d_in[2];
    const float* bq    = (const float*)d_in[3];
    const float* wk    = (const float*)d_in[4];
    const float* bk    = (const float*)d_in[5];
    const float* wv    = (const float*)d_in[6];
    const float* bv    = (const float*)d_in[7];
    const float* w_out = (const float*)d_in[8];
    const float* b_out = (const float*)d_in[9];
    float* outp = (float*)d_out;

    const size_t MB = 1024 * 1024;
    ushort_t* xn = (ushort_t*)d_out;             // bytes [0,16MB), dead after qkv
    ushort_t* H  = (ushort_t*)d_out + 8 * MB;    // heads bf16, bytes [16MB,32MB)
    char* ws = (char*)d_ws;

    ln_kernel<<<dim3(8192), 256, 0, stream>>>(x, xn);

    if (ws_size >= 58 * MB) {
        ushort_t* qb  = (ushort_t*)ws;             // 16 MB (dead after pv)
        ushort_t* kb  = (ushort_t*)(ws + 16 * MB); // 16 MB (dead after pv)
        ushort_t* vtb = (ushort_t*)(ws + 32 * MB); // 16 MB
        float* csum   = (float*)(ws + 48 * MB);    // 512 KB
        ushort_t* wqb = (ushort_t*)(ws + 49 * MB);
        ushort_t* wkb = (ushort_t*)(ws + 51 * MB);
        ushort_t* wvb = (ushort_t*)(ws + 53 * MB);
        ushort_t* wob = (ushort_t*)(ws + 55 * MB);
        float* ofull  = (float*)ws;                // 32 MB fp32 out (aliases qb/kb)
        wconv<<<dim3(1024), 256, 0, stream>>>(wq, wqb);
        wconv<<<dim3(1024), 256, 0, stream>>>(wk, wkb);
        wconv<<<dim3(1024), 256, 0, stream>>>(wv, wvb);
        wconv<<<dim3(1024), 256, 0, stream>>>(w_out, wob);
        gemm_mfma<0, 0><<<dim3(8, 64, 3), 256, 0, stream>>>(
            xn, wqb, wkb, wvb, bq, bk, bv, qb, kb, vtb, nullptr, nullptr, 1, 0, 0);
        colstats_mfma<<<dim3(16, 128), 256, 0, stream>>>(qb, kb, mask, 0, csum);
        pv_mfma<<<dim3(16, 128), 256, 0, stream>>>(qb, kb, vtb, mask, 0, csum, H, 0);
        gemm_mfma<0, 1><<<dim3(8, 64), 256, 0, stream>>>(
            H, wob, wob, wob, b_out, b_out, b_out, nullptr, nullptr, nullptr,
            ofull, x, 0, 0, 0);
        hipMemcpyAsync(d_out, ofull, 32 * MB, hipMemcpyDeviceToDevice, stream);
    } else {
        // compact path: <= 6.07 MB ws; in-place cascade out-proj (R4/R6-proven)
        ushort_t* qb  = (ushort_t*)ws;            // 2 MB
        ushort_t* kb  = (ushort_t*)(ws + 2 * MB); // 2 MB
        ushort_t* vtb = (ushort_t*)(ws + 4 * MB); // 2 MB
        float* csum   = (float*)(ws + 6 * MB);    // 64 KB
        ushort_t* hcopy = (ushort_t*)ws;          // 256KB tail copy (qb dead)
        const int casc[6][2] = {{0, 32},   {4096, 16}, {6144, 8},
                                {7168, 4}, {7680, 2},  {7936, 1}};
        for (int g = 0; g < 8; g++) {
            gemm_mfma<1, 0><<<dim3(8, 8, 3), 256, 0, stream>>>(
                xn + (size_t)g * MB, wq, wk, wv, bq, bk, bv, qb, kb, vtb,
                nullptr, nullptr, 0, 0, 0);
            colstats_mfma<<<dim3(16, 16), 256, 0, stream>>>(qb, kb, mask,
                                                            g * 1024, csum);
            pv_mfma<<<dim3(16, 16), 256, 0, stream>>>(qb, kb, vtb, mask,
                                                      g * 1024, csum, H, g * 1024);
        }
        tailcopy<<<dim3(64), 256, 0, stream>>>((const us8*)(H + (size_t)8064 * 1024),
                                               (us8*)hcopy);
        for (int i = 0; i < 6; i++)
            gemm_mfma<1, 1><<<dim3(8, casc[i][1]), 256, 0, stream>>>(
                H, w_out, w_out, w_out, b_out, b_out, b_out, nullptr, nullptr,
                nullptr, outp, x, 0, casc[i][0], 0);
        gemm_mfma<1, 1><<<dim3(8, 1), 256, 0, stream>>>(
            hcopy, w_out, w_out, w_out, b_out, b_out, b_out, nullptr, nullptr,
            nullptr, outp, x, 0, 8064, 8064);
    }
}